// Round 1
// baseline (334.103 us; speedup 1.0000x reference)
//
#include <hip/hip_runtime.h>

typedef unsigned short u16;
typedef unsigned int u32;
typedef __bf16 bf16x8 __attribute__((ext_vector_type(8)));
typedef float f32x4 __attribute__((ext_vector_type(4)));
typedef u32 u32x4 __attribute__((ext_vector_type(4)));

#define CIN 256
#define COUT_ 256
#define HW 56
#define LIMG 3136          // 56*56
#define CDIM 2304          // 256*9
#define NKSTEP 36          // 2304 / 64

// round-to-nearest-even f32 -> bf16 bits (no NaN inputs here)
static __device__ __forceinline__ u16 f32_bf16(float f) {
    u32 u = __float_as_uint(f);
    u += 0x7fffu + ((u >> 16) & 1u);
    return (u16)(u >> 16);
}

// ---------------------------------------------------------------------------
// Weight quant: w (COUT, CDIM) -> wq stored as [o][k'] bf16, transposed view
// wmat[c][o] = w[o][c]; block quant over (32 c) x (32 o); levels = 127.
// Stored pre-swizzled: k' = k ^ ((o&7)<<3)  (XOR of 16B-slot within 64-k group)
// so the GEMM can stage with linear global_load_lds and read with the same XOR.
// ---------------------------------------------------------------------------
__global__ void quant_w_kernel(const float* __restrict__ w, u16* __restrict__ wq) {
    const int kb = blockIdx.x % 72;   // cdim block (32 wide)
    const int ob = blockIdx.x / 72;   // cout block (32 wide)
    const int k0 = kb * 32, o0 = ob * 32;
    const int t = threadIdx.x;        // 64 threads
    float v[16];
    float mx = 0.f;
#pragma unroll
    for (int i = 0; i < 16; ++i) {
        const int e = i * 64 + t;     // 0..1023
        const int oo = e >> 5, cc = e & 31;
        const float val = w[(o0 + oo) * CDIM + k0 + cc];
        v[i] = val;
        mx = fmaxf(mx, fabsf(val));
    }
#pragma unroll
    for (int d = 1; d < 64; d <<= 1) mx = fmaxf(mx, __shfl_xor(mx, d, 64));
    const float scale = mx > 0.f ? mx * (1.f / 127.f) : 1.f;
    const float inv   = mx > 0.f ? 127.f / mx : 1.f;
#pragma unroll
    for (int i = 0; i < 16; ++i) {
        const int e = i * 64 + t;
        const int oo = e >> 5, cc = e & 31;
        const int o = o0 + oo, k = k0 + cc;
        const float q = rintf(v[i] * inv) * scale;
        wq[o * CDIM + (k ^ ((o & 7) << 3))] = f32_bf16(q);
    }
}

// ---------------------------------------------------------------------------
// Fused implicit-GEMM conv with on-the-fly input unfold + (1,32) block quant.
// Tile: BM=64 rows (m = b*3136 + l), BN=256 (all of COUT), BK=64.
// 256 threads = 4 waves in a 2x2 (M x N) grid; each wave 32x128 via 16x16x32.
// ---------------------------------------------------------------------------
__global__ __launch_bounds__(256, 3)
void conv_gemm_kernel(const float* __restrict__ x, const u16* __restrict__ wq,
                      const float* __restrict__ bias, float* __restrict__ out) {
    __shared__ __align__(16) u16 As[64][72];     // +8 pad breaks pow2 stride
    __shared__ __align__(16) u16 Bs[256 * 64];   // [col][64 k] swizzled slots
    __shared__ float smax[256];

    const int tid = threadIdx.x;
    const int m0 = blockIdx.x * 64;
    const int img = m0 / LIMG;           // block-uniform (64 | 3136)
    const int l0 = m0 % LIMG;

    const int lane = tid & 63;
    const int q = __builtin_amdgcn_readfirstlane(tid >> 6);  // wave id 0..3
    const int wm = q & 1, wn = q >> 1;

    // this thread's A-row (pixel) for staging
    const int l = l0 + lane;
    const int oh = l / HW, ow = l % HW;
    const bool okh0 = (oh >= 1), okh2 = (oh <= HW - 2);
    const bool okw0 = (ow >= 1), okw2 = (ow <= HW - 2);
    const float* __restrict__ xim = x + (size_t)img * (CIN * LIMG);

    f32x4 acc[2][8];
#pragma unroll
    for (int m = 0; m < 2; ++m)
#pragma unroll
        for (int n = 0; n < 8; ++n)
            acc[m][n] = (f32x4){0.f, 0.f, 0.f, 0.f};

    for (int t = 0; t < NKSTEP; ++t) {
        const int k0 = t * 64;
        const int fbase = k0 + q * 16;   // wave-uniform

        // ---- gather 16 unfolded features (row `lane`, quarter q) ----
        float vals[16];
        float mx = 0.f;
#pragma unroll
        for (int j = 0; j < 16; ++j) {
            const int f = fbase + j;         // uniform -> SALU chain
            const int c = f / 9;
            const int r9 = f - c * 9;
            const int kh = r9 / 3;
            const int kw = r9 - kh * 3;
            const int dsp = (kh - 1) * HW + (kw - 1);
            const bool okh = (kh == 0) ? okh0 : ((kh == 2) ? okh2 : true);
            const bool okw = (kw == 0) ? okw0 : ((kw == 2) ? okw2 : true);
            float v = 0.f;
            if (okh && okw) v = xim[c * LIMG + l + dsp];
            vals[j] = v;
            mx = fmaxf(mx, fabsf(v));
        }

        __syncthreads();  // (1) all waves done reading As/Bs of prev step

        smax[tid] = mx;
        // ---- stage B tile: 256 cols x 64 k, linear (source pre-swizzled) ----
#pragma unroll
        for (int i = 0; i < 8; ++i) {
            const int colt = i * 32 + (tid >> 3);
            const int slot = tid & 7;
            const u16* g = wq + (size_t)colt * CDIM + k0 + slot * 8;
            u16* lp = &Bs[0] + (size_t)i * 2048 + (size_t)tid * 8;
            __builtin_amdgcn_global_load_lds(
                (const __attribute__((address_space(1))) void*)g,
                (__attribute__((address_space(3))) void*)lp, 16, 0, 0);
        }

        __syncthreads();  // (2) smax visible

        // ---- finish (1,32)-block quant: pair quarter q with q^1 ----
        const float pm = smax[tid ^ 64];
        const float m2 = fmaxf(mx, pm);
        const float scale = m2 > 0.f ? m2 * (1.f / 127.f) : 1.f;
        const float inv   = m2 > 0.f ? 127.f / m2 : 1.f;

        union { u16 h[16]; u32x4 v4[2]; } pk;
#pragma unroll
        for (int j = 0; j < 16; ++j) {
            const float r = rintf(vals[j] * inv);
            pk.h[j] = f32_bf16(r * scale);
        }
        *(u32x4*)&As[lane][q * 16]     = pk.v4[0];
        *(u32x4*)&As[lane][q * 16 + 8] = pk.v4[1];

        __syncthreads();  // (3) As written; barrier drains vmcnt -> Bs landed

        // ---- MFMA: wave computes 32 rows x 128 cols ----
        const int arow = wm * 32 + (lane & 15);
        const int ak = (lane >> 4) << 3;
#pragma unroll
        for (int kk = 0; kk < 2; ++kk) {
            const bf16x8 a0 = *(const bf16x8*)&As[arow][kk * 32 + ak];
            const bf16x8 a1 = *(const bf16x8*)&As[arow + 16][kk * 32 + ak];
            const int slot = kk * 4 + (lane >> 4);
#pragma unroll
            for (int n = 0; n < 8; ++n) {
                const int col = wn * 128 + n * 16 + (lane & 15);
                const bf16x8 b = *(const bf16x8*)&Bs[col * 64 + ((slot ^ (col & 7)) << 3)];
                acc[0][n] = __builtin_amdgcn_mfma_f32_16x16x32_bf16(a0, b, acc[0][n], 0, 0, 0);
                acc[1][n] = __builtin_amdgcn_mfma_f32_16x16x32_bf16(a1, b, acc[1][n], 0, 0, 0);
            }
        }
    }

    // ---- epilogue: bias + store (NCHW); 4 consecutive l per lane -> float4 ----
#pragma unroll
    for (int n = 0; n < 8; ++n) {
        const int col = wn * 128 + n * 16 + (lane & 15);
        const float bz = bias[col];
#pragma unroll
        for (int m = 0; m < 2; ++m) {
            f32x4 a = acc[m][n];
            a[0] += bz; a[1] += bz; a[2] += bz; a[3] += bz;
            const int row = wm * 32 + m * 16 + ((lane >> 4) << 2);
            const size_t idx = ((size_t)(img * COUT_ + col)) * LIMG + l0 + row;
            *(f32x4*)(out + idx) = a;
        }
    }
}

extern "C" void kernel_launch(void* const* d_in, const int* in_sizes, int n_in,
                              void* d_out, int out_size, void* d_ws, size_t ws_size,
                              hipStream_t stream) {
    const float* x    = (const float*)d_in[0];
    const float* w    = (const float*)d_in[1];
    const float* bias = (const float*)d_in[2];
    float* out = (float*)d_out;
    u16* wq = (u16*)d_ws;   // 2304*256*2 B = 1.18 MB

    quant_w_kernel<<<576, 64, 0, stream>>>(w, wq);
    conv_gemm_kernel<<<784, 256, 0, stream>>>(x, wq, bias, out);
}

// Round 3
// 264.875 us; speedup vs baseline: 1.2614x; 1.2614x over previous
//
#include <hip/hip_runtime.h>

typedef unsigned short u16;
typedef unsigned int u32;
typedef __bf16 bf16x8 __attribute__((ext_vector_type(8)));
typedef float f32x4 __attribute__((ext_vector_type(4)));
typedef u32 u32x4 __attribute__((ext_vector_type(4)));

#define CIN 256
#define COUT_ 256
#define HW 56
#define LIMG 3136          // 56*56
#define CDIM 2304          // 256*9
#define NK 36              // 2304 / 64

// round-to-nearest-even f32 -> bf16 bits (no NaN inputs here)
static __device__ __forceinline__ u16 f32_bf16(float f) {
    u32 u = __float_as_uint(f);
    u += 0x7fffu + ((u >> 16) & 1u);
    return (u16)(u >> 16);
}

// ---------------------------------------------------------------------------
// Weight quant: w (COUT, CDIM) -> wq[o][k'] bf16, k' = k ^ ((o&7)<<3)
// (pre-swizzled so GEMM stages with linear global_load_lds and reads with
//  the same XOR -> bank-conflict-free, both-sides-or-neither rule)
// ---------------------------------------------------------------------------
__global__ void quant_w_kernel(const float* __restrict__ w, u16* __restrict__ wq) {
    const int kb = blockIdx.x % 72;   // cdim block (32 wide)
    const int ob = blockIdx.x / 72;   // cout block (32 wide)
    const int k0 = kb * 32, o0 = ob * 32;
    const int t = threadIdx.x;        // 64 threads
    float v[16];
    float mx = 0.f;
#pragma unroll
    for (int i = 0; i < 16; ++i) {
        const int e = i * 64 + t;     // 0..1023
        const int oo = e >> 5, cc = e & 31;
        const float val = w[(o0 + oo) * CDIM + k0 + cc];
        v[i] = val;
        mx = fmaxf(mx, fabsf(val));
    }
#pragma unroll
    for (int d = 1; d < 64; d <<= 1) mx = fmaxf(mx, __shfl_xor(mx, d, 64));
    const float scale = mx > 0.f ? mx * (1.f / 127.f) : 1.f;
    const float inv   = mx > 0.f ? 127.f / mx : 1.f;
#pragma unroll
    for (int i = 0; i < 16; ++i) {
        const int e = i * 64 + t;
        const int oo = e >> 5, cc = e & 31;
        const int o = o0 + oo, k = k0 + cc;
        const float q = rintf(v[i] * inv) * scale;
        wq[o * CDIM + (k ^ ((o & 7) << 3))] = f32_bf16(q);
    }
}

// ---------------------------------------------------------------------------
// Fused implicit-GEMM conv, software-pipelined (depth-1 prefetch, raw
// s_barrier + counted vmcnt so loads stay in flight across barriers).
// Tile: BM=64 (rows = pixels), BN=256 (all COUT), BK=64. 256 thr = 4 waves.
// ---------------------------------------------------------------------------
__global__ __launch_bounds__(256, 3)
void conv_gemm_kernel(const float* __restrict__ x, const u16* __restrict__ wq,
                      const float* __restrict__ bias, float* __restrict__ out) {
    __shared__ __align__(16) u16 Bs[256 * 64];   // [col][slot^] 32 KB
    __shared__ __align__(16) u16 As[64 * 64];    // [row][slot^(row&7)] 8 KB
    __shared__ float smax[256];

    const int tid = threadIdx.x;
    const int lane = tid & 63;
    const int q = __builtin_amdgcn_readfirstlane(tid >> 6);  // wave 0..3
    const int wm = q & 1, wn = q >> 1;

    const int m0 = blockIdx.x * 64;
    const int img = m0 / LIMG;                   // block-uniform (64 | 3136)
    const int l0 = m0 - img * LIMG;

    const int l = l0 + lane;                     // this thread's pixel row
    const int oh = l / HW, ow = l - oh * HW;
    // 9-bit validity mask over kernel positions p = kh*3+kw
    u32 pb = 0;
#pragma unroll
    for (int p = 0; p < 9; ++p) {
        const int kh = p / 3, kw = p - (p / 3) * 3;
        const int ih = oh + kh - 1, iw = ow + kw - 1;
        const u32 ok = (ih >= 0 && ih < HW && iw >= 0 && iw < HW) ? 1u : 0u;
        pb |= ok << p;
    }
    const float* __restrict__ xim = x + (size_t)img * (CIN * LIMG);

    f32x4 acc[2][8];
#pragma unroll
    for (int m = 0; m < 2; ++m)
#pragma unroll
        for (int n = 0; n < 8; ++n)
            acc[m][n] = (f32x4){0.f, 0.f, 0.f, 0.f};

    float valsA[16], valsB[16];

    // issue raw gather loads for tile t (values masked at consume time)
    auto gather_issue = [&](float (&vals)[16], int t) {
#pragma unroll
        for (int j = 0; j < 16; ++j) {
            const int f = t * 64 + (q << 4) + j;   // wave-uniform -> SALU
            const int c = f / 9;
            const int r9 = f - c * 9;
            const int kh = r9 / 3;
            const int kw = r9 - kh * 3;
            const int dsp = (kh - 1) * HW + (kw - 1);
            int e = l + dsp;
            e = min(max(e, 0), LIMG - 1);          // fault-safe clamp
            vals[j] = xim[(u32)(c * LIMG + e)];
        }
    };

    auto step = [&](int t, float (&vC)[16], float (&vN)[16], bool last) {
        // ---- (1) stage B tile t (linear gload_lds; source pre-swizzled) ----
#pragma unroll
        for (int i = 0; i < 8; ++i) {
            const int colt = i * 32 + (tid >> 3);
            const u16* g = wq + (size_t)colt * CDIM + t * 64 + (tid & 7) * 8;
            u16* lp = &Bs[0] + i * 2048 + tid * 8;
            __builtin_amdgcn_global_load_lds(
                (const __attribute__((address_space(1))) void*)g,
                (__attribute__((address_space(3))) void*)lp, 16, 0, 0);
        }
        // fence: keep gather issue AFTER the gload_lds (vmcnt(16) counting)
        asm volatile("" ::: "memory");
        __builtin_amdgcn_sched_barrier(0);

        // ---- (2) issue gather for t+1 ----
        if (!last) gather_issue(vN, t + 1);

        // ---- (3a) consume vals(t): mask + local max ----
        float vm[16];
        float mx = 0.f;
#pragma unroll
        for (int j = 0; j < 16; ++j) {
            const int f = t * 64 + (q << 4) + j;
            const int c = f / 9;
            const int r9 = f - c * 9;                 // uniform (SGPR)
            const u32 bit = (pb >> r9) & 1u;          // per-lane
            const float v = __uint_as_float(__float_as_uint(vC[j]) & (0u - bit));
            vm[j] = v;
            mx = fmaxf(mx, fabsf(v));
        }
        smax[tid] = mx;
        asm volatile("s_waitcnt lgkmcnt(0)" ::: "memory");
        __builtin_amdgcn_sched_barrier(0);
        __builtin_amdgcn_s_barrier();                 // barrier 1 (smax)
        __builtin_amdgcn_sched_barrier(0);

        // ---- (3c) finish (1,32)-block quant, write As (XOR-swizzled) ----
        const float pm = smax[tid ^ 64];
        const float m2 = fmaxf(mx, pm);
        const float inv = m2 > 0.f ? __builtin_amdgcn_rcpf(m2) * 127.f : 0.f;
        const float scale = m2 * (1.f / 127.f);
        union { u16 h[16]; u32x4 v4[2]; } pk;
#pragma unroll
        for (int j = 0; j < 16; ++j) {
            const float r = rintf(vm[j] * inv);
            pk.h[j] = f32_bf16(r * scale);
        }
        {
            const int s0 = q * 2;
            *(u32x4*)&As[lane * 64 + (((s0    ) ^ (lane & 7)) << 3)] = pk.v4[0];
            *(u32x4*)&As[lane * 64 + (((s0 + 1) ^ (lane & 7)) << 3)] = pk.v4[1];
        }
        // counted vmcnt: drains B-stage(t) (8 loads) but leaves the 16
        // gather(t+1) loads in flight. Last iter: full drain.
        if (!last) { asm volatile("s_waitcnt lgkmcnt(0) vmcnt(16)" ::: "memory"); }
        else       { asm volatile("s_waitcnt lgkmcnt(0) vmcnt(0)"  ::: "memory"); }
        __builtin_amdgcn_sched_barrier(0);
        __builtin_amdgcn_s_barrier();                 // barrier 2 (As/Bs ready)
        __builtin_amdgcn_sched_barrier(0);

        // ---- (5) MFMA: wave computes 32 rows x 128 cols ----
        const int arow = wm * 32 + (lane & 15);
#pragma unroll
        for (int kk = 0; kk < 2; ++kk) {
            const int s = kk * 4 + (lane >> 4);
            const bf16x8 a0 = *(const bf16x8*)&As[(arow     ) * 64 + ((s ^ ((arow     ) & 7)) << 3)];
            const bf16x8 a1 = *(const bf16x8*)&As[(arow + 16) * 64 + ((s ^ ((arow + 16) & 7)) << 3)];
#pragma unroll
            for (int n = 0; n < 8; ++n) {
                const int col = wn * 128 + n * 16 + (lane & 15);
                const bf16x8 b = *(const bf16x8*)&Bs[col * 64 + ((s ^ (col & 7)) << 3)];
                acc[0][n] = __builtin_amdgcn_mfma_f32_16x16x32_bf16(a0, b, acc[0][n], 0, 0, 0);
                acc[1][n] = __builtin_amdgcn_mfma_f32_16x16x32_bf16(a1, b, acc[1][n], 0, 0, 0);
            }
        }
        __builtin_amdgcn_sched_barrier(0);
        __builtin_amdgcn_s_barrier();                 // barrier 3 (reuse guard)
        __builtin_amdgcn_sched_barrier(0);
    };

    // prologue: issue gather(0)
    gather_issue(valsA, 0);

#pragma unroll 1
    for (int p = 0; p < 17; ++p) {
        step(2 * p,     valsA, valsB, false);
        step(2 * p + 1, valsB, valsA, false);
    }
    step(34, valsA, valsB, false);
    step(35, valsB, valsA, true);

    // ---- epilogue: bias + store (NCHW); 4 consecutive l per lane ----
#pragma unroll
    for (int n = 0; n < 8; ++n) {
        const int col = wn * 128 + n * 16 + (lane & 15);
        const float bz = bias[col];
#pragma unroll
        for (int m = 0; m < 2; ++m) {
            f32x4 a = acc[m][n];
            a[0] += bz; a[1] += bz; a[2] += bz; a[3] += bz;
            const int row = wm * 32 + m * 16 + ((lane >> 4) << 2);
            const size_t idx = ((size_t)(img * COUT_ + col)) * LIMG + l0 + row;
            *(f32x4*)(out + idx) = a;
        }
    }
}

extern "C" void kernel_launch(void* const* d_in, const int* in_sizes, int n_in,
                              void* d_out, int out_size, void* d_ws, size_t ws_size,
                              hipStream_t stream) {
    const float* x    = (const float*)d_in[0];
    const float* w    = (const float*)d_in[1];
    const float* bias = (const float*)d_in[2];
    float* out = (float*)d_out;
    u16* wq = (u16*)d_ws;   // 2304*256*2 B = 1.18 MB

    quant_w_kernel<<<576, 64, 0, stream>>>(w, wq);
    conv_gemm_kernel<<<784, 256, 0, stream>>>(x, wq, bias, out);
}

// Round 6
// 259.721 us; speedup vs baseline: 1.2864x; 1.0198x over previous
//
#include <hip/hip_runtime.h>

typedef unsigned short u16;
typedef unsigned int u32;
typedef __bf16 bf16x8 __attribute__((ext_vector_type(8)));
typedef float f32x4 __attribute__((ext_vector_type(4)));
typedef u32 u32x4 __attribute__((ext_vector_type(4)));

#define CIN 256
#define COUT_ 256
#define HW 56
#define LIMG 3136          // 56*56
#define CDIM 2304          // 256*9
#define NSTEP 36           // 2304 / 64
#define NTILE 392          // 16*3136 / 128

// round-to-nearest-even f32 -> bf16 bits
static __device__ __forceinline__ u16 f32_bf16(float f) {
    u32 u = __float_as_uint(f);
    u += 0x7fffu + ((u >> 16) & 1u);
    return (u16)(u >> 16);
}

// ---------------------------------------------------------------------------
// Weight quant: w (COUT, CDIM) -> wq[o][k'] bf16, k' = k ^ ((o&7)<<3)
// (pre-swizzled so GEMM stages with linear global_load_lds and reads with
//  the same XOR -> bank-conflict-free) — unchanged from R3 (verified).
// ---------------------------------------------------------------------------
__global__ void quant_w_kernel(const float* __restrict__ w, u16* __restrict__ wq) {
    const int kb = blockIdx.x % 72;
    const int ob = blockIdx.x / 72;
    const int k0 = kb * 32, o0 = ob * 32;
    const int t = threadIdx.x;        // 64 threads
    float v[16];
    float mx = 0.f;
#pragma unroll
    for (int i = 0; i < 16; ++i) {
        const int e = i * 64 + t;
        const int oo = e >> 5, cc = e & 31;
        const float val = w[(o0 + oo) * CDIM + k0 + cc];
        v[i] = val;
        mx = fmaxf(mx, fabsf(val));
    }
#pragma unroll
    for (int d = 1; d < 64; d <<= 1) mx = fmaxf(mx, __shfl_xor(mx, d, 64));
    const float scale = mx > 0.f ? mx * (1.f / 127.f) : 1.f;
    const float inv   = mx > 0.f ? 127.f / mx : 1.f;
#pragma unroll
    for (int i = 0; i < 16; ++i) {
        const int e = i * 64 + t;
        const int oo = e >> 5, cc = e & 31;
        const int o = o0 + oo, k = k0 + cc;
        const float q = rintf(v[i] * inv) * scale;
        wq[o * CDIM + (k ^ ((o & 7) << 3))] = f32_bf16(q);
    }
}

// ---------------------------------------------------------------------------
// Fused implicit-GEMM conv. BM=128, BN=256, BK=64. 256 thr = 4 waves (2x2),
// wave tile 64x128. Thread-local (1,32) input quant (thread = one block).
// Gathers are NORMAL loads (compiler-tracked waits; RA-safe). Manual waits
// only pre-barrier for cross-wave As/Bs visibility. 2 barriers/step.
// ---------------------------------------------------------------------------
__global__ __launch_bounds__(256, 2)
void conv_gemm_kernel(const float* __restrict__ x, const u16* __restrict__ wq,
                      const float* __restrict__ bias, float* __restrict__ out) {
    __shared__ __align__(16) u16 Bs[256 * 64];   // [col][slot^] 32 KB
    __shared__ __align__(16) u16 As[128 * 64];   // [row][slot^(row&7)] 16 KB

    const int tid  = threadIdx.x;
    const int lane = tid & 63;
    const int wid  = __builtin_amdgcn_readfirstlane(tid >> 6);  // 0..3
    const int wm   = wid & 1;        // M-half of wave grid
    const int wn   = wid >> 1;       // N-half; also the k-half h for staging
    const int h    = wn;

    // XCD-aware tile swizzle (392 = 8*49, bijective)
    const int tile = (blockIdx.x & 7) * 49 + (blockIdx.x >> 3);
    const int m0   = tile * 128;

    // staging row for this thread: r = wm*64 + lane
    const int r = wm * 64 + lane;
    const int m = m0 + r;
    const int img = m / 3136;
    const int l   = m - img * 3136;
    const int oh  = l / HW, ow = l - (l / HW) * HW;

    // 9-bit validity mask over kernel positions p = kh*3+kw
    u32 pb = 0;
#pragma unroll
    for (int p = 0; p < 9; ++p) {
        const int kh = p / 3, kw = p - (p / 3) * 3;
        const int ih = oh + kh - 1, iw = ow + kw - 1;
        const u32 ok = (ih >= 0 && ih < HW && iw >= 0 && iw < HW) ? 1u : 0u;
        pb |= ok << p;
    }
    const float* __restrict__ xim = x + (size_t)img * (CIN * LIMG);

    f32x4 acc[4][8];
#pragma unroll
    for (int mi = 0; mi < 4; ++mi)
#pragma unroll
        for (int n = 0; n < 8; ++n)
            acc[mi][n] = (f32x4){0.f, 0.f, 0.f, 0.f};

    float va[32];

    // gather 32 features for step t: normal loads, clamped index (fault-free;
    // invalid positions masked at consume via pb)
    auto gather_issue = [&](int t) {
#pragma unroll
        for (int j = 0; j < 32; ++j) {
            const int k = t * 64 + h * 32 + j;    // wave-uniform -> SALU
            const int c = k / 9;
            const int p = k - c * 9;
            const int kh = p / 3;
            const int dsp = (kh - 1) * HW + (p - kh * 3) - 1;
            int e = l + dsp;                      // per-lane
            e = min(max(e, 0), LIMG - 1);
            va[j] = xim[(u32)(c * LIMG + e)];
        }
    };

    // prologue: gathers for step 0
    gather_issue(0);

#pragma unroll 1
    for (int t = 0; t < NSTEP; ++t) {
        // ---- (1) stage B tile t (linear gload_lds; source pre-swizzled) ----
#pragma unroll
        for (int i = 0; i < 8; ++i) {
            const int colt = i * 32 + (tid >> 3);
            const u16* g = wq + (size_t)colt * CDIM + t * 64 + (tid & 7) * 8;
            u16* lp = &Bs[0] + i * 2048 + tid * 8;
            __builtin_amdgcn_global_load_lds(
                (const __attribute__((address_space(1))) void*)g,
                (__attribute__((address_space(3))) void*)lp, 16, 0, 0);
        }
        asm volatile("" ::: "memory");            // pin: gloads before gathers
        __builtin_amdgcn_sched_barrier(0);

        // ---- (2) consume va(t): mask in place, max, quantize, write As ----
#pragma unroll
        for (int j = 0; j < 32; ++j) {
            const int k = t * 64 + h * 32 + j;
            const int c = k / 9;                  // uniform
            const int p = k - c * 9;              // uniform
            const u32 bit = (pb >> p) & 1u;       // per-lane
            va[j] = __uint_as_float(__float_as_uint(va[j]) & (0u - bit));
        }
        float t16[16];
#pragma unroll
        for (int j = 0; j < 16; ++j) t16[j] = fmaxf(fabsf(va[j]), fabsf(va[j + 16]));
#pragma unroll
        for (int j = 0; j < 8; ++j) t16[j] = fmaxf(t16[j], t16[j + 8]);
#pragma unroll
        for (int j = 0; j < 4; ++j) t16[j] = fmaxf(t16[j], t16[j + 4]);
        const float mx = fmaxf(fmaxf(t16[0], t16[1]), fmaxf(t16[2], t16[3]));

        const float inv   = mx > 0.f ? 127.f * __builtin_amdgcn_rcpf(mx) : 0.f;
        const float scale = mx * (1.f / 127.f);

        union { u16 hh[32]; u32x4 v4[4]; } pk;
#pragma unroll
        for (int j = 0; j < 32; ++j)
            pk.hh[j] = f32_bf16(rintf(va[j] * inv) * scale);
#pragma unroll
        for (int w = 0; w < 4; ++w) {
            const int s = h * 4 + w;
            *(u32x4*)&As[r * 64 + ((s ^ (r & 7)) << 3)] = pk.v4[w];
        }
        asm volatile("" ::: "memory");            // pin: As writes done issuing
        __builtin_amdgcn_sched_barrier(0);

        // ---- (3) issue gathers for t+1 (in flight across barriers) ----
        if (t < NSTEP - 1) {
            gather_issue(t + 1);
            // drain As ds_writes + the 8 gloads (oldest VMEM); keep the 32
            // newest (the gathers) in flight. Extra RA spill ops issued after
            // the gathers only make this MORE conservative on the gloads.
            asm volatile("s_waitcnt lgkmcnt(0) vmcnt(32)" ::: "memory");
        } else {
            asm volatile("s_waitcnt lgkmcnt(0) vmcnt(0)" ::: "memory");
        }
        __builtin_amdgcn_sched_barrier(0);
        __builtin_amdgcn_s_barrier();             // As/Bs ready (cross-wave)
        asm volatile("" ::: "memory");
        __builtin_amdgcn_sched_barrier(0);

        // ---- (4) MFMA: wave computes 64 rows x 128 cols ----
        const int arow_b = wm * 64 + (lane & 15);
        const int bcol_b = wn * 128 + (lane & 15);
        const int sl = lane >> 4;
#pragma unroll
        for (int kk = 0; kk < 2; ++kk) {
            const int s = kk * 4 + sl;
            bf16x8 a[4];
#pragma unroll
            for (int mi = 0; mi < 4; ++mi) {
                const int ar = arow_b + mi * 16;
                a[mi] = *(const bf16x8*)&As[ar * 64 + ((s ^ (ar & 7)) << 3)];
            }
#pragma unroll
            for (int n = 0; n < 8; ++n) {
                const int col = bcol_b + n * 16;
                const bf16x8 b = *(const bf16x8*)&Bs[col * 64 + ((s ^ (col & 7)) << 3)];
#pragma unroll
                for (int mi = 0; mi < 4; ++mi)
                    acc[mi][n] = __builtin_amdgcn_mfma_f32_16x16x32_bf16(a[mi], b, acc[mi][n], 0, 0, 0);
            }
        }
        asm volatile("" ::: "memory");
        __builtin_amdgcn_sched_barrier(0);
        __builtin_amdgcn_s_barrier();             // MFMA done: As/Bs reusable
        asm volatile("" ::: "memory");
        __builtin_amdgcn_sched_barrier(0);
    }

    // ---- epilogue: bias + store NCHW ----
    const int si    = __builtin_amdgcn_readfirstlane(m0 / 3136);
    const int l0    = m0 - si * 3136;
    const bool split = l0 > 3136 - 128;           // tile crosses image boundary
    const int rb = wm * 64 + ((lane >> 4) << 2);
#pragma unroll
    for (int n = 0; n < 8; ++n) {
        const int col = wn * 128 + n * 16 + (lane & 15);
        const float bz = bias[col];
#pragma unroll
        for (int mi = 0; mi < 4; ++mi) {
            f32x4 a = acc[mi][n];
            a[0] += bz; a[1] += bz; a[2] += bz; a[3] += bz;
            const int row = rb + mi * 16;
            if (!split) {
                *(f32x4*)&out[((size_t)(si * COUT_ + col)) * LIMG + l0 + row] = a;
            } else {
#pragma unroll
                for (int j = 0; j < 4; ++j) {
                    const int mm = m0 + row + j;
                    const int ig = mm / 3136;
                    const int ll = mm - ig * 3136;
                    out[((size_t)(ig * COUT_ + col)) * LIMG + ll] = a[j];
                }
            }
        }
    }
}

extern "C" void kernel_launch(void* const* d_in, const int* in_sizes, int n_in,
                              void* d_out, int out_size, void* d_ws, size_t ws_size,
                              hipStream_t stream) {
    const float* x    = (const float*)d_in[0];
    const float* w    = (const float*)d_in[1];
    const float* bias = (const float*)d_in[2];
    float* out = (float*)d_out;
    u16* wq = (u16*)d_ws;   // 2304*256*2 B = 1.18 MB

    quant_w_kernel<<<576, 64, 0, stream>>>(w, wq);
    conv_gemm_kernel<<<NTILE, 256, 0, stream>>>(x, wq, bias, out);
}